// Round 4
// baseline (350.957 us; speedup 1.0000x reference)
//
#include <hip/hip_runtime.h>

// MultiHeadAttention: B=4, S=2048, D=1024, H=16, DK=64
// cvt x->bf16; transpose weights->bf16 [N][K]; QK GEMM (swapped C^T epilogue),
// V GEMM (normal, writes V^T [B,H,DK,S]); flash attention 128 q-rows/block;
// output GEMM (swapped, float4 stores). All GEMMs: BK=64, XOR-swizzled LDS,
// global_load_lds width-16 staging.

typedef __attribute__((ext_vector_type(8))) short short8;
typedef __attribute__((ext_vector_type(4))) float floatx4;
typedef __attribute__((ext_vector_type(4))) unsigned short ushort4v;

__device__ __forceinline__ unsigned short f2bf(float f) {
    unsigned int u = __float_as_uint(f);
    unsigned int r = (u + 0x7fffu + ((u >> 16) & 1u)) >> 16;
    return (unsigned short)r;
}

__device__ __forceinline__ void gll16(const unsigned short* g, unsigned short* l) {
    __builtin_amdgcn_global_load_lds(
        (const __attribute__((address_space(1))) unsigned int*)g,
        (__attribute__((address_space(3))) unsigned int*)l, 16, 0, 0);
}

// ---------------- convert x (fp32 -> bf16) ----------------
__global__ void cvtx_kernel(const float* __restrict__ x, unsigned short* __restrict__ xb) {
    int i = (blockIdx.x * 256 + threadIdx.x) * 4;
    float4 v = *(const float4*)&x[i];
    ushort4v o;
    o.x = f2bf(v.x); o.y = f2bf(v.y); o.z = f2bf(v.z); o.w = f2bf(v.w);
    *(ushort4v*)&xb[i] = o;
}

// ---------------- transpose + convert weight: w[K][N] fp32 -> wt[N][K] bf16 ----------------
__global__ void wtrans_kernel(const float* __restrict__ w, unsigned short* __restrict__ wt) {
    __shared__ float t[32][33];
    int kb = blockIdx.y * 32, nb = blockIdx.x * 32;
    int col = threadIdx.x & 31, rw = threadIdx.x >> 5;
#pragma unroll
    for (int i = 0; i < 4; i++) {
        int row = rw + i * 8;
        t[row][col] = w[(kb + row) * 1024 + nb + col];
    }
    __syncthreads();
#pragma unroll
    for (int i = 0; i < 4; i++) {
        int row = rw + i * 8;
        wt[(nb + row) * 1024 + kb + col] = f2bf(t[col][row]);
    }
}

// ---------------- GEMM core: BK=64, XOR-swizzled LDS, 32 MFMA per barrier ----------------
// SW=true: acc[mt][nt] = C^T tile (rows=features quad*4+r, cols=tokens l15)
__device__ __forceinline__ short8 ldsr(const unsigned short* p) { return *(const short8*)p; }

template <bool SW>
__device__ __forceinline__ void gemm_core(const unsigned short* __restrict__ A,
                                          const unsigned short* __restrict__ Bt,
                                          unsigned short* As, unsigned short* Bs,
                                          int m0, int n0, int K, floatx4 (&acc)[4][4]) {
    int tid = threadIdx.x;
    int lane = tid & 63, wave = tid >> 6;
    int wr = wave >> 1, wc = wave & 1;
    int quad = lane >> 4, l15 = lane & 15, l7 = l15 & 7;
    int rsub = lane >> 3;            // 0..7
    int gl = (lane & 7) ^ rsub;      // logical k-granule feeding this lane's phys slot
    floatx4 zero4 = {0.f, 0.f, 0.f, 0.f};
#pragma unroll
    for (int i = 0; i < 4; i++)
#pragma unroll
        for (int j = 0; j < 4; j++) acc[i][j] = zero4;

    for (int k0 = 0; k0 < K; k0 += 64) {
#pragma unroll
        for (int p = 0; p < 4; p++) {
            int idx = (wave * 4 + p) * 64 + lane;   // granule slot 0..1023
            int row = (wave * 4 + p) * 8 + rsub;    // 0..127 (row&7 == rsub)
            gll16(&A[(m0 + row) * K + k0 + gl * 8], &As[idx * 8]);
            gll16(&Bt[(n0 + row) * K + k0 + gl * 8], &Bs[idx * 8]);
        }
        __syncthreads();
#pragma unroll
        for (int kk = 0; kk < 2; kk++) {
            short8 af[4], bf[4];
#pragma unroll
            for (int mt = 0; mt < 4; mt++) {
                int r = wr * 64 + mt * 16 + l15;
                af[mt] = ldsr(&As[r * 64 + (((kk * 4 + quad) ^ l7) * 8)]);
            }
#pragma unroll
            for (int nt = 0; nt < 4; nt++) {
                int r = wc * 64 + nt * 16 + l15;
                bf[nt] = ldsr(&Bs[r * 64 + (((kk * 4 + quad) ^ l7) * 8)]);
            }
#pragma unroll
            for (int mt = 0; mt < 4; mt++)
#pragma unroll
                for (int nt = 0; nt < 4; nt++) {
                    if (SW)
                        acc[mt][nt] = __builtin_amdgcn_mfma_f32_16x16x32_bf16(bf[nt], af[mt], acc[mt][nt], 0, 0, 0);
                    else
                        acc[mt][nt] = __builtin_amdgcn_mfma_f32_16x16x32_bf16(af[mt], bf[nt], acc[mt][nt], 0, 0, 0);
                }
        }
        __syncthreads();
    }
}

// ---------------- Q/K GEMM (swapped): N spans wtq|wtk (2048 rows) ----------------
__global__ __launch_bounds__(256) void gemm_qk_kernel(
    const unsigned short* __restrict__ xb, const unsigned short* __restrict__ wt,
    const float* __restrict__ bq, const float* __restrict__ bk,
    unsigned short* __restrict__ qo, unsigned short* __restrict__ ko) {
    __shared__ __align__(16) unsigned short As[128 * 64];
    __shared__ __align__(16) unsigned short Bs[128 * 64];
    int m0 = blockIdx.y * 128, n0 = blockIdx.x * 128;
    floatx4 acc[4][4];
    gemm_core<true>(xb, wt, As, Bs, m0, n0, 1024, acc);

    int which = n0 >> 10;
    const float* bias = which ? bk : bq;
    unsigned short* dst = which ? ko : qo;
    int tid = threadIdx.x, lane = tid & 63, wave = tid >> 6;
    int wr = wave >> 1, wc = wave & 1, quad = lane >> 4, l15 = lane & 15;
#pragma unroll
    for (int mt = 0; mt < 4; mt++)
#pragma unroll
        for (int nt = 0; nt < 4; nt++) {
            int tok = m0 + wr * 64 + mt * 16 + l15;
            int b = tok >> 11, s = tok & 2047;
            int colf = (n0 + wc * 64 + nt * 16 + quad * 4) & 1023;
            float4 bb = *(const float4*)&bias[colf];
            int h = colf >> 6, dk = colf & 63;
            ushort4v o;
            o.x = f2bf(acc[mt][nt][0] + bb.x);
            o.y = f2bf(acc[mt][nt][1] + bb.y);
            o.z = f2bf(acc[mt][nt][2] + bb.z);
            o.w = f2bf(acc[mt][nt][3] + bb.w);
            *(ushort4v*)&dst[((long)((b * 16 + h) * 2048 + s)) * 64 + dk] = o;
        }
}

// ---------------- V GEMM (normal): writes V^T [B,H,DK,S] ----------------
__global__ __launch_bounds__(256) void gemm_v_kernel(
    const unsigned short* __restrict__ xb, const unsigned short* __restrict__ wtv,
    const float* __restrict__ bv, unsigned short* __restrict__ vo) {
    __shared__ __align__(16) unsigned short As[128 * 64];
    __shared__ __align__(16) unsigned short Bs[128 * 64];
    int m0 = blockIdx.y * 128, n0 = blockIdx.x * 128;
    floatx4 acc[4][4];
    gemm_core<false>(xb, wtv, As, Bs, m0, n0, 1024, acc);

    int tid = threadIdx.x, lane = tid & 63, wave = tid >> 6;
    int wr = wave >> 1, wc = wave & 1, quad = lane >> 4, l15 = lane & 15;
#pragma unroll
    for (int mt = 0; mt < 4; mt++)
#pragma unroll
        for (int nt = 0; nt < 4; nt++) {
            int tok0 = m0 + wr * 64 + mt * 16 + quad * 4;  // 4 consecutive tokens
            int b = tok0 >> 11, s = tok0 & 2047;
            int colf = n0 + wc * 64 + nt * 16 + l15;
            int h = colf >> 6, dk = colf & 63;
            float bb = bv[colf];
            ushort4v o;
            o.x = f2bf(acc[mt][nt][0] + bb);
            o.y = f2bf(acc[mt][nt][1] + bb);
            o.z = f2bf(acc[mt][nt][2] + bb);
            o.w = f2bf(acc[mt][nt][3] + bb);
            *(ushort4v*)&vo[((long)((b * 16 + h) * 64 + dk)) * 2048 + s] = o;
        }
}

// ---------------- output GEMM (swapped): fp32 out, float4 stores ----------------
__global__ __launch_bounds__(256) void gemm_out_kernel(
    const unsigned short* __restrict__ ob, const unsigned short* __restrict__ wto,
    const float* __restrict__ bo, float* __restrict__ out) {
    __shared__ __align__(16) unsigned short As[128 * 64];
    __shared__ __align__(16) unsigned short Bs[128 * 64];
    int m0 = blockIdx.y * 128, n0 = blockIdx.x * 128;
    floatx4 acc[4][4];
    gemm_core<true>(ob, wto, As, Bs, m0, n0, 1024, acc);

    int tid = threadIdx.x, lane = tid & 63, wave = tid >> 6;
    int wr = wave >> 1, wc = wave & 1, quad = lane >> 4, l15 = lane & 15;
#pragma unroll
    for (int mt = 0; mt < 4; mt++)
#pragma unroll
        for (int nt = 0; nt < 4; nt++) {
            int tok = m0 + wr * 64 + mt * 16 + l15;
            int cg = n0 + wc * 64 + nt * 16 + quad * 4;
            float4 bb = *(const float4*)&bo[cg];
            float4 o;
            o.x = acc[mt][nt][0] + bb.x;
            o.y = acc[mt][nt][1] + bb.y;
            o.z = acc[mt][nt][2] + bb.z;
            o.w = acc[mt][nt][3] + bb.w;
            *(float4*)&out[(long)tok * 1024 + cg] = o;
        }
}

// ---------------- flash attention (causal), 128 q-rows/block ----------------
// Per wave: 2 q-subtiles (16 rows each). K/V frags shared across subtiles.
// S^T = K Q^T -> per-lane softmax (2 shfls) -> P LDS round trip -> O^T = V^T P^T.
#define PLS 72

__device__ __forceinline__ void stage_kv(const unsigned short* __restrict__ Kg,
                                         const unsigned short* __restrict__ Vg,
                                         unsigned short* Ks, unsigned short* Vs,
                                         int lane, int wave) {
    int rsub = lane >> 3;
    int g = (lane & 7) ^ rsub;
#pragma unroll
    for (int p = 0; p < 2; p++) {
        int chunk = wave * 2 + p;
        int r = chunk * 8 + rsub;
        gll16(&Kg[r * 64 + g * 8], &Ks[chunk * 512]);
        gll16(&Vg[r * 2048 + g * 8], &Vs[chunk * 512]);
    }
}

__global__ __launch_bounds__(256) void attn_kernel(
    const unsigned short* __restrict__ Q, const unsigned short* __restrict__ Kk,
    const unsigned short* __restrict__ Vt, unsigned short* __restrict__ O) {
    __shared__ __align__(16) unsigned short Ks[2][8 * 512];
    __shared__ __align__(16) unsigned short Vs[2][8 * 512];
    __shared__ __align__(16) unsigned short Ps[4 * 16 * PLS];

    int bid = blockIdx.x;
    int qt = 15 - (bid >> 6);        // heavy q-tiles first
    int bh = bid & 63;
    int q0 = qt * 128;
    long base = (long)bh * 2048 * 64;   // Q, K: [bh][s][dk]
    long vbase = (long)bh * 64 * 2048;  // Vt:   [bh][dk][s]
    int tid = threadIdx.x, lane = tid & 63, wave = tid >> 6;
    int quad = lane >> 4, l15 = lane & 15, l7 = l15 & 7;
    const float SCL = 0.125f * 1.44269504f;

    short8 qfA[2], qfB[2];
    int qrA = q0 + wave * 16 + l15;
    int qrB = qrA + 64;
    qfA[0] = *(const short8*)&Q[base + qrA * 64 + quad * 8];
    qfA[1] = *(const short8*)&Q[base + qrA * 64 + 32 + quad * 8];
    qfB[0] = *(const short8*)&Q[base + qrB * 64 + quad * 8];
    qfB[1] = *(const short8*)&Q[base + qrB * 64 + 32 + quad * 8];

    float mA = -1e30f, lA = 0.f, mB = -1e30f, lB = 0.f;
    floatx4 oA[4], oB[4];
    floatx4 zero4 = {0.f, 0.f, 0.f, 0.f};
#pragma unroll
    for (int st = 0; st < 4; st++) { oA[st] = zero4; oB[st] = zero4; }

    unsigned short* myP = &Ps[(wave * 16) * PLS];
    int ktmax = 2 * qt + 1;

    stage_kv(&Kk[base], &Vt[vbase], Ks[0], Vs[0], lane, wave);
    __syncthreads();

    for (int kt = 0; kt <= ktmax; kt++) {
        int cur = kt & 1;
        if (kt < ktmax)
            stage_kv(&Kk[base + (long)(kt + 1) * 64 * 64], &Vt[vbase + (kt + 1) * 64],
                     Ks[cur ^ 1], Vs[cur ^ 1], lane, wave);
        bool doA = (kt < ktmax);   // subtile A covers kt <= 2*qt

        // shared K frags -> scores for both subtiles
        floatx4 saA[4], saB[4];
#pragma unroll
        for (int st = 0; st < 4; st++) {
            int row = st * 16 + l15;
            short8 kf0 = ldsr(&Ks[cur][row * 64 + ((quad ^ l7) * 8)]);
            short8 kf1 = ldsr(&Ks[cur][row * 64 + (((4 + quad) ^ l7) * 8)]);
            saB[st] = __builtin_amdgcn_mfma_f32_16x16x32_bf16(kf0, qfB[0], zero4, 0, 0, 0);
            saB[st] = __builtin_amdgcn_mfma_f32_16x16x32_bf16(kf1, qfB[1], saB[st], 0, 0, 0);
            if (doA) {
                saA[st] = __builtin_amdgcn_mfma_f32_16x16x32_bf16(kf0, qfA[0], zero4, 0, 0, 0);
                saA[st] = __builtin_amdgcn_mfma_f32_16x16x32_bf16(kf1, qfA[1], saA[st], 0, 0, 0);
            }
        }

        // softmax + P frags, subtile B
        short8 pfB0, pfB1, pfA0, pfA1;
        {
            float t[4][4];
            float rm = -1e30f;
#pragma unroll
            for (int st = 0; st < 4; st++)
#pragma unroll
                for (int r = 0; r < 4; r++) {
                    int kg = kt * 64 + st * 16 + quad * 4 + r;
                    float v = (kg > qrB) ? -1e30f : saB[st][r] * SCL;
                    t[st][r] = v;
                    rm = fmaxf(rm, v);
                }
            rm = fmaxf(rm, __shfl_xor(rm, 16, 64));
            rm = fmaxf(rm, __shfl_xor(rm, 32, 64));
            float mn = fmaxf(mB, rm);
            float alpha = exp2f(mB - mn);
            float rs = 0.f;
#pragma unroll
            for (int st = 0; st < 4; st++)
#pragma unroll
                for (int r = 0; r < 4; r++) {
                    float p = exp2f(t[st][r] - mn);
                    t[st][r] = p;
                    rs += p;
                }
            rs += __shfl_xor(rs, 16, 64);
            rs += __shfl_xor(rs, 32, 64);
            lB = lB * alpha + rs;
            mB = mn;
#pragma unroll
            for (int st = 0; st < 4; st++)
#pragma unroll
                for (int r = 0; r < 4; r++) oB[st][r] *= alpha;
#pragma unroll
            for (int st = 0; st < 4; st++) {
                ushort4v pk;
                pk.x = f2bf(t[st][0]); pk.y = f2bf(t[st][1]);
                pk.z = f2bf(t[st][2]); pk.w = f2bf(t[st][3]);
                *(ushort4v*)&myP[l15 * PLS + st * 16 + quad * 4] = pk;
            }
            pfB0 = ldsr(&myP[l15 * PLS + quad * 8]);
            pfB1 = ldsr(&myP[l15 * PLS + 32 + quad * 8]);
        }
        // softmax + P frags, subtile A
        if (doA) {
            float t[4][4];
            float rm = -1e30f;
#pragma unroll
            for (int st = 0; st < 4; st++)
#pragma unroll
                for (int r = 0; r < 4; r++) {
                    int kg = kt * 64 + st * 16 + quad * 4 + r;
                    float v = (kg > qrA) ? -1e30f : saA[st][r] * SCL;
                    t[st][r] = v;
                    rm = fmaxf(rm, v);
                }
            rm = fmaxf(rm, __shfl_xor(rm, 16, 64));
            rm = fmaxf(rm, __shfl_xor(rm, 32, 64));
            float mn = fmaxf(mA, rm);
            float alpha = exp2f(mA - mn);
            float rs = 0.f;
#pragma unroll
            for (int st = 0; st < 4; st++)
#pragma unroll
                for (int r = 0; r < 4; r++) {
                    float p = exp2f(t[st][r] - mn);
                    t[st][r] = p;
                    rs += p;
                }
            rs += __shfl_xor(rs, 16, 64);
            rs += __shfl_xor(rs, 32, 64);
            lA = lA * alpha + rs;
            mA = mn;
#pragma unroll
            for (int st = 0; st < 4; st++)
#pragma unroll
                for (int r = 0; r < 4; r++) oA[st][r] *= alpha;
#pragma unroll
            for (int st = 0; st < 4; st++) {
                ushort4v pk;
                pk.x = f2bf(t[st][0]); pk.y = f2bf(t[st][1]);
                pk.z = f2bf(t[st][2]); pk.w = f2bf(t[st][3]);
                *(ushort4v*)&myP[l15 * PLS + st * 16 + quad * 4] = pk;
            }
            pfA0 = ldsr(&myP[l15 * PLS + quad * 8]);
            pfA1 = ldsr(&myP[l15 * PLS + 32 + quad * 8]);
        }

        // shared V frags -> O^T += V^T P^T for both subtiles
#pragma unroll
        for (int st = 0; st < 4; st++) {
            int row = st * 16 + l15;
            short8 vf0 = ldsr(&Vs[cur][row * 64 + ((quad ^ l7) * 8)]);
            short8 vf1 = ldsr(&Vs[cur][row * 64 + (((4 + quad) ^ l7) * 8)]);
            oB[st] = __builtin_amdgcn_mfma_f32_16x16x32_bf16(vf0, pfB0, oB[st], 0, 0, 0);
            oB[st] = __builtin_amdgcn_mfma_f32_16x16x32_bf16(vf1, pfB1, oB[st], 0, 0, 0);
            if (doA) {
                oA[st] = __builtin_amdgcn_mfma_f32_16x16x32_bf16(vf0, pfA0, oA[st], 0, 0, 0);
                oA[st] = __builtin_amdgcn_mfma_f32_16x16x32_bf16(vf1, pfA1, oA[st], 0, 0, 0);
            }
        }
        __syncthreads();
    }

    // epilogue: O^T regs -> O[b,s,h*64+dk] bf16, 8B stores
    int b = bh >> 4, h = bh & 15;
    float invA = 1.f / lA, invB = 1.f / lB;
#pragma unroll
    for (int st = 0; st < 4; st++) {
        ushort4v ov;
        ov.x = f2bf(oA[st][0] * invA); ov.y = f2bf(oA[st][1] * invA);
        ov.z = f2bf(oA[st][2] * invA); ov.w = f2bf(oA[st][3] * invA);
        *(ushort4v*)&O[((long)(b * 2048 + qrA)) * 1024 + h * 64 + st * 16 + quad * 4] = ov;
        ushort4v ow;
        ow.x = f2bf(oB[st][0] * invB); ow.y = f2bf(oB[st][1] * invB);
        ow.z = f2bf(oB[st][2] * invB); ow.w = f2bf(oB[st][3] * invB);
        *(ushort4v*)&O[((long)(b * 2048 + qrB)) * 1024 + h * 64 + st * 16 + quad * 4] = ow;
    }
}

// ---------------- launch ----------------
extern "C" void kernel_launch(void* const* d_in, const int* in_sizes, int n_in,
                              void* d_out, int out_size, void* d_ws, size_t ws_size,
                              hipStream_t stream) {
    const float* x  = (const float*)d_in[0];
    const float* wq = (const float*)d_in[1];
    const float* bq = (const float*)d_in[2];
    const float* wk = (const float*)d_in[3];
    const float* bk = (const float*)d_in[4];
    const float* wv = (const float*)d_in[5];
    const float* bv = (const float*)d_in[6];
    const float* wo = (const float*)d_in[7];
    const float* bo = (const float*)d_in[8];

    char* w = (char*)d_ws;
    unsigned short* xb  = (unsigned short*)w;                    // 16MB
    unsigned short* wtq = (unsigned short*)(w + (16u << 20));    // wtq|wtk contiguous (qk GEMM N-dim)
    unsigned short* wtk = wtq + (1u << 20);
    unsigned short* wtv = wtk + (1u << 20);
    unsigned short* wto = wtv + (1u << 20);
    unsigned short* qb  = wto + (1u << 20);
    unsigned short* kb  = qb + (8u << 20);
    unsigned short* vb  = kb + (8u << 20);                       // V^T [B,H,DK,S]
    unsigned short* ob  = vb + (8u << 20);

    cvtx_kernel<<<8192, 256, 0, stream>>>(x, xb);
    dim3 tg(32, 32);
    wtrans_kernel<<<tg, 256, 0, stream>>>(wq, wtq);
    wtrans_kernel<<<tg, 256, 0, stream>>>(wk, wtk);
    wtrans_kernel<<<tg, 256, 0, stream>>>(wv, wtv);
    wtrans_kernel<<<tg, 256, 0, stream>>>(wo, wto);
    gemm_qk_kernel<<<dim3(16, 64), 256, 0, stream>>>(xb, wtq, bq, bk, qb, kb);
    gemm_v_kernel<<<dim3(8, 64), 256, 0, stream>>>(xb, wtv, bv, vb);
    attn_kernel<<<1024, 256, 0, stream>>>(qb, kb, vb, ob);
    gemm_out_kernel<<<dim3(8, 64), 256, 0, stream>>>(ob, wto, bo, (float*)d_out);
}

// Round 5
// 315.703 us; speedup vs baseline: 1.1117x; 1.1117x over previous
//
#include <hip/hip_runtime.h>

// MultiHeadAttention: B=4, S=2048, D=1024, H=16, DK=64
// cvt x->bf16; transpose weights->bf16 [N][K]; QK GEMM (swapped C^T epilogue),
// V GEMM (normal, writes V^T [B,H,DK,S]); flash attention 128 q-rows/block
// (no-running-max softmax, v_perm packed bf16, 40KB LDS = 4 blocks/CU);
// output GEMM (swapped, float4 stores). All GEMMs: BK=64, XOR-swizzled LDS,
// global_load_lds width-16 staging.

typedef __attribute__((ext_vector_type(8))) short short8;
typedef __attribute__((ext_vector_type(4))) float floatx4;
typedef __attribute__((ext_vector_type(4))) unsigned short ushort4v;

__device__ __forceinline__ unsigned short f2bf(float f) {
    unsigned int u = __float_as_uint(f);
    unsigned int r = (u + 0x7fffu + ((u >> 16) & 1u)) >> 16;
    return (unsigned short)r;
}

// pack two fp32 -> two bf16 (truncate) in one v_perm_b32
__device__ __forceinline__ unsigned int pk2bf(float lo, float hi) {
    return __builtin_amdgcn_perm(__float_as_uint(hi), __float_as_uint(lo), 0x07060302u);
}

__device__ __forceinline__ void gll16(const unsigned short* g, unsigned short* l) {
    __builtin_amdgcn_global_load_lds(
        (const __attribute__((address_space(1))) unsigned int*)g,
        (__attribute__((address_space(3))) unsigned int*)l, 16, 0, 0);
}

// ---------------- convert x (fp32 -> bf16) ----------------
__global__ void cvtx_kernel(const float* __restrict__ x, unsigned short* __restrict__ xb) {
    int i = (blockIdx.x * 256 + threadIdx.x) * 4;
    float4 v = *(const float4*)&x[i];
    ushort4v o;
    o.x = f2bf(v.x); o.y = f2bf(v.y); o.z = f2bf(v.z); o.w = f2bf(v.w);
    *(ushort4v*)&xb[i] = o;
}

// ---------------- transpose + convert weight: w[K][N] fp32 -> wt[N][K] bf16 ----------------
__global__ void wtrans_kernel(const float* __restrict__ w, unsigned short* __restrict__ wt) {
    __shared__ float t[32][33];
    int kb = blockIdx.y * 32, nb = blockIdx.x * 32;
    int col = threadIdx.x & 31, rw = threadIdx.x >> 5;
#pragma unroll
    for (int i = 0; i < 4; i++) {
        int row = rw + i * 8;
        t[row][col] = w[(kb + row) * 1024 + nb + col];
    }
    __syncthreads();
#pragma unroll
    for (int i = 0; i < 4; i++) {
        int row = rw + i * 8;
        wt[(nb + row) * 1024 + kb + col] = f2bf(t[col][row]);
    }
}

// ---------------- GEMM core: BK=64, XOR-swizzled LDS, 32 MFMA per barrier ----------------
__device__ __forceinline__ short8 ldsr(const unsigned short* p) { return *(const short8*)p; }

template <bool SW>
__device__ __forceinline__ void gemm_core(const unsigned short* __restrict__ A,
                                          const unsigned short* __restrict__ Bt,
                                          unsigned short* As, unsigned short* Bs,
                                          int m0, int n0, int K, floatx4 (&acc)[4][4]) {
    int tid = threadIdx.x;
    int lane = tid & 63, wave = tid >> 6;
    int wr = wave >> 1, wc = wave & 1;
    int quad = lane >> 4, l15 = lane & 15, l7 = l15 & 7;
    int rsub = lane >> 3;
    int gl = (lane & 7) ^ rsub;
    floatx4 zero4 = {0.f, 0.f, 0.f, 0.f};
#pragma unroll
    for (int i = 0; i < 4; i++)
#pragma unroll
        for (int j = 0; j < 4; j++) acc[i][j] = zero4;

    for (int k0 = 0; k0 < K; k0 += 64) {
#pragma unroll
        for (int p = 0; p < 4; p++) {
            int idx = (wave * 4 + p) * 64 + lane;
            int row = (wave * 4 + p) * 8 + rsub;
            gll16(&A[(m0 + row) * K + k0 + gl * 8], &As[idx * 8]);
            gll16(&Bt[(n0 + row) * K + k0 + gl * 8], &Bs[idx * 8]);
        }
        __syncthreads();
#pragma unroll
        for (int kk = 0; kk < 2; kk++) {
            short8 af[4], bf[4];
#pragma unroll
            for (int mt = 0; mt < 4; mt++) {
                int r = wr * 64 + mt * 16 + l15;
                af[mt] = ldsr(&As[r * 64 + (((kk * 4 + quad) ^ l7) * 8)]);
            }
#pragma unroll
            for (int nt = 0; nt < 4; nt++) {
                int r = wc * 64 + nt * 16 + l15;
                bf[nt] = ldsr(&Bs[r * 64 + (((kk * 4 + quad) ^ l7) * 8)]);
            }
#pragma unroll
            for (int mt = 0; mt < 4; mt++)
#pragma unroll
                for (int nt = 0; nt < 4; nt++) {
                    if (SW)
                        acc[mt][nt] = __builtin_amdgcn_mfma_f32_16x16x32_bf16(bf[nt], af[mt], acc[mt][nt], 0, 0, 0);
                    else
                        acc[mt][nt] = __builtin_amdgcn_mfma_f32_16x16x32_bf16(af[mt], bf[nt], acc[mt][nt], 0, 0, 0);
                }
        }
        __syncthreads();
    }
}

// ---------------- Q/K GEMM (swapped): N spans wtq|wtk (2048 rows) ----------------
__global__ __launch_bounds__(256) void gemm_qk_kernel(
    const unsigned short* __restrict__ xb, const unsigned short* __restrict__ wt,
    const float* __restrict__ bq, const float* __restrict__ bk,
    unsigned short* __restrict__ qo, unsigned short* __restrict__ ko) {
    __shared__ __align__(16) unsigned short As[128 * 64];
    __shared__ __align__(16) unsigned short Bs[128 * 64];
    int m0 = blockIdx.y * 128, n0 = blockIdx.x * 128;
    floatx4 acc[4][4];
    gemm_core<true>(xb, wt, As, Bs, m0, n0, 1024, acc);

    int which = n0 >> 10;
    const float* bias = which ? bk : bq;
    unsigned short* dst = which ? ko : qo;
    int tid = threadIdx.x, lane = tid & 63, wave = tid >> 6;
    int wr = wave >> 1, wc = wave & 1, quad = lane >> 4, l15 = lane & 15;
#pragma unroll
    for (int mt = 0; mt < 4; mt++)
#pragma unroll
        for (int nt = 0; nt < 4; nt++) {
            int tok = m0 + wr * 64 + mt * 16 + l15;
            int b = tok >> 11, s = tok & 2047;
            int colf = (n0 + wc * 64 + nt * 16 + quad * 4) & 1023;
            float4 bb = *(const float4*)&bias[colf];
            int h = colf >> 6, dk = colf & 63;
            ushort4v o;
            o.x = f2bf(acc[mt][nt][0] + bb.x);
            o.y = f2bf(acc[mt][nt][1] + bb.y);
            o.z = f2bf(acc[mt][nt][2] + bb.z);
            o.w = f2bf(acc[mt][nt][3] + bb.w);
            *(ushort4v*)&dst[((long)((b * 16 + h) * 2048 + s)) * 64 + dk] = o;
        }
}

// ---------------- V GEMM (normal): writes V^T [B,H,DK,S] ----------------
__global__ __launch_bounds__(256) void gemm_v_kernel(
    const unsigned short* __restrict__ xb, const unsigned short* __restrict__ wtv,
    const float* __restrict__ bv, unsigned short* __restrict__ vo) {
    __shared__ __align__(16) unsigned short As[128 * 64];
    __shared__ __align__(16) unsigned short Bs[128 * 64];
    int m0 = blockIdx.y * 128, n0 = blockIdx.x * 128;
    floatx4 acc[4][4];
    gemm_core<false>(xb, wtv, As, Bs, m0, n0, 1024, acc);

    int tid = threadIdx.x, lane = tid & 63, wave = tid >> 6;
    int wr = wave >> 1, wc = wave & 1, quad = lane >> 4, l15 = lane & 15;
#pragma unroll
    for (int mt = 0; mt < 4; mt++)
#pragma unroll
        for (int nt = 0; nt < 4; nt++) {
            int tok0 = m0 + wr * 64 + mt * 16 + quad * 4;
            int b = tok0 >> 11, s = tok0 & 2047;
            int colf = n0 + wc * 64 + nt * 16 + l15;
            int h = colf >> 6, dk = colf & 63;
            float bb = bv[colf];
            ushort4v o;
            o.x = f2bf(acc[mt][nt][0] + bb);
            o.y = f2bf(acc[mt][nt][1] + bb);
            o.z = f2bf(acc[mt][nt][2] + bb);
            o.w = f2bf(acc[mt][nt][3] + bb);
            *(ushort4v*)&vo[((long)((b * 16 + h) * 64 + dk)) * 2048 + s] = o;
        }
}

// ---------------- output GEMM (swapped): fp32 out, float4 stores ----------------
__global__ __launch_bounds__(256) void gemm_out_kernel(
    const unsigned short* __restrict__ ob, const unsigned short* __restrict__ wto,
    const float* __restrict__ bo, float* __restrict__ out) {
    __shared__ __align__(16) unsigned short As[128 * 64];
    __shared__ __align__(16) unsigned short Bs[128 * 64];
    int m0 = blockIdx.y * 128, n0 = blockIdx.x * 128;
    floatx4 acc[4][4];
    gemm_core<true>(ob, wto, As, Bs, m0, n0, 1024, acc);

    int tid = threadIdx.x, lane = tid & 63, wave = tid >> 6;
    int wr = wave >> 1, wc = wave & 1, quad = lane >> 4, l15 = lane & 15;
#pragma unroll
    for (int mt = 0; mt < 4; mt++)
#pragma unroll
        for (int nt = 0; nt < 4; nt++) {
            int tok = m0 + wr * 64 + mt * 16 + l15;
            int cg = n0 + wc * 64 + nt * 16 + quad * 4;
            float4 bb = *(const float4*)&bo[cg];
            float4 o;
            o.x = acc[mt][nt][0] + bb.x;
            o.y = acc[mt][nt][1] + bb.y;
            o.z = acc[mt][nt][2] + bb.z;
            o.w = acc[mt][nt][3] + bb.w;
            *(float4*)&out[(long)tok * 1024 + cg] = o;
        }
}

// ---------------- flash attention (causal), 128 q-rows/block ----------------
// No-running-max softmax: p = exp2(s*SCL) masked to 0; l = sum(p). Valid since
// |s*SCL| <~ 9 -> exp2 <= ~512, sums <~ 4e3, all well inside fp32 range.
__device__ __forceinline__ void stage_kv(const unsigned short* __restrict__ Kg,
                                         const unsigned short* __restrict__ Vg,
                                         unsigned short* Ks, unsigned short* Vs,
                                         int lane, int wave) {
    int rsub = lane >> 3;
    int g = (lane & 7) ^ rsub;
#pragma unroll
    for (int p = 0; p < 2; p++) {
        int chunk = wave * 2 + p;
        int r = chunk * 8 + rsub;
        gll16(&Kg[r * 64 + g * 8], &Ks[chunk * 512]);
        gll16(&Vg[r * 2048 + g * 8], &Vs[chunk * 512]);
    }
}

__global__ __launch_bounds__(256, 4) void attn_kernel(
    const unsigned short* __restrict__ Q, const unsigned short* __restrict__ Kk,
    const unsigned short* __restrict__ Vt, unsigned short* __restrict__ O) {
    __shared__ __align__(16) unsigned short Ks[2][8 * 512];
    __shared__ __align__(16) unsigned short Vs[2][8 * 512];
    __shared__ __align__(16) unsigned short Ps[4 * 16 * 64];  // XOR-swizzled, 8KB

    int bid = blockIdx.x;
    int qt = 15 - (bid >> 6);        // heavy q-tiles first
    int bh = bid & 63;
    int q0 = qt * 128;
    long base = (long)bh * 2048 * 64;   // Q, K: [bh][s][dk]
    long vbase = (long)bh * 64 * 2048;  // Vt:   [bh][dk][s]
    int tid = threadIdx.x, lane = tid & 63, wave = tid >> 6;
    int quad = lane >> 4, l15 = lane & 15, l7 = l15 & 7;
    const float SCL = 0.125f * 1.44269504f;

    short8 qfA[2], qfB[2];
    int qrA = q0 + wave * 16 + l15;
    int qrB = qrA + 64;
    qfA[0] = *(const short8*)&Q[base + qrA * 64 + quad * 8];
    qfA[1] = *(const short8*)&Q[base + qrA * 64 + 32 + quad * 8];
    qfB[0] = *(const short8*)&Q[base + qrB * 64 + quad * 8];
    qfB[1] = *(const short8*)&Q[base + qrB * 64 + 32 + quad * 8];

    float lA = 0.f, lB = 0.f;
    floatx4 oA[4], oB[4];
    floatx4 zero4 = {0.f, 0.f, 0.f, 0.f};
#pragma unroll
    for (int st = 0; st < 4; st++) { oA[st] = zero4; oB[st] = zero4; }

    unsigned short* myP = &Ps[(wave * 16) * 64];
    // P LDS addresses (XOR-swizzled granules, stride 64 elems = 32 banks)
    int pw_off = l15 * 64 + (quad & 1) * 4;   // + physg*8 per st
    int pr0 = l15 * 64 + ((quad ^ l7) * 8);
    int pr1 = l15 * 64 + (((4 + quad) ^ l7) * 8);

    int ktmax = 2 * qt + 1;
    stage_kv(&Kk[base], &Vt[vbase], Ks[0], Vs[0], lane, wave);
    __syncthreads();

    for (int kt = 0; kt <= ktmax; kt++) {
        int cur = kt & 1;
        if (kt < ktmax)
            stage_kv(&Kk[base + (long)(kt + 1) * 64 * 64], &Vt[vbase + (kt + 1) * 64],
                     Ks[cur ^ 1], Vs[cur ^ 1], lane, wave);
        bool doA = (kt < ktmax);

        // shared K frags -> scores for both subtiles
        floatx4 saA[4], saB[4];
#pragma unroll
        for (int st = 0; st < 4; st++) {
            int row = st * 16 + l15;
            short8 kf0 = ldsr(&Ks[cur][row * 64 + ((quad ^ l7) * 8)]);
            short8 kf1 = ldsr(&Ks[cur][row * 64 + (((4 + quad) ^ l7) * 8)]);
            saB[st] = __builtin_amdgcn_mfma_f32_16x16x32_bf16(kf0, qfB[0], zero4, 0, 0, 0);
            saB[st] = __builtin_amdgcn_mfma_f32_16x16x32_bf16(kf1, qfB[1], saB[st], 0, 0, 0);
            if (doA) {
                saA[st] = __builtin_amdgcn_mfma_f32_16x16x32_bf16(kf0, qfA[0], zero4, 0, 0, 0);
                saA[st] = __builtin_amdgcn_mfma_f32_16x16x32_bf16(kf1, qfA[1], saA[st], 0, 0, 0);
            }
        }

        int kg0 = kt * 64 + quad * 4;
        short8 pfB0, pfB1, pfA0, pfA1;
        // subtile B softmax (no max subtraction)
        {
            float p[4][4];
            float rs = 0.f;
#pragma unroll
            for (int st = 0; st < 4; st++)
#pragma unroll
                for (int r = 0; r < 4; r++) {
                    float pe = exp2f(saB[st][r] * SCL);
                    pe = (kg0 + st * 16 + r > qrB) ? 0.f : pe;
                    p[st][r] = pe;
                    rs += pe;
                }
            rs += __shfl_xor(rs, 16, 64);
            rs += __shfl_xor(rs, 32, 64);
            lB += rs;
#pragma unroll
            for (int st = 0; st < 4; st++) {
                uint2 pw;
                pw.x = pk2bf(p[st][0], p[st][1]);
                pw.y = pk2bf(p[st][2], p[st][3]);
                *(uint2*)&myP[pw_off + (((st * 2 + (quad >> 1)) ^ l7) * 8)] = pw;
            }
            pfB0 = ldsr(&myP[pr0]);
            pfB1 = ldsr(&myP[pr1]);
        }
        // subtile A softmax
        if (doA) {
            float p[4][4];
            float rs = 0.f;
#pragma unroll
            for (int st = 0; st < 4; st++)
#pragma unroll
                for (int r = 0; r < 4; r++) {
                    float pe = exp2f(saA[st][r] * SCL);
                    pe = (kg0 + st * 16 + r > qrA) ? 0.f : pe;
                    p[st][r] = pe;
                    rs += pe;
                }
            rs += __shfl_xor(rs, 16, 64);
            rs += __shfl_xor(rs, 32, 64);
            lA += rs;
#pragma unroll
            for (int st = 0; st < 4; st++) {
                uint2 pw;
                pw.x = pk2bf(p[st][0], p[st][1]);
                pw.y = pk2bf(p[st][2], p[st][3]);
                *(uint2*)&myP[pw_off + (((st * 2 + (quad >> 1)) ^ l7) * 8)] = pw;
            }
            pfA0 = ldsr(&myP[pr0]);
            pfA1 = ldsr(&myP[pr1]);
        }

        // shared V frags -> O^T += V^T P^T for both subtiles
#pragma unroll
        for (int st = 0; st < 4; st++) {
            int row = st * 16 + l15;
            short8 vf0 = ldsr(&Vs[cur][row * 64 + ((quad ^ l7) * 8)]);
            short8 vf1 = ldsr(&Vs[cur][row * 64 + (((4 + quad) ^ l7) * 8)]);
            oB[st] = __builtin_amdgcn_mfma_f32_16x16x32_bf16(vf0, pfB0, oB[st], 0, 0, 0);
            oB[st] = __builtin_amdgcn_mfma_f32_16x16x32_bf16(vf1, pfB1, oB[st], 0, 0, 0);
            if (doA) {
                oA[st] = __builtin_amdgcn_mfma_f32_16x16x32_bf16(vf0, pfA0, oA[st], 0, 0, 0);
                oA[st] = __builtin_amdgcn_mfma_f32_16x16x32_bf16(vf1, pfA1, oA[st], 0, 0, 0);
            }
        }
        __syncthreads();
    }

    // epilogue: O^T regs -> O[b,s,h*64+dk] bf16, 8B stores
    int b = bh >> 4, h = bh & 15;
    float invA = 1.f / lA, invB = 1.f / lB;
#pragma unroll
    for (int st = 0; st < 4; st++) {
        uint2 ov;
        ov.x = pk2bf(oA[st][0] * invA, oA[st][1] * invA);
        ov.y = pk2bf(oA[st][2] * invA, oA[st][3] * invA);
        *(uint2*)&O[((long)(b * 2048 + qrA)) * 1024 + h * 64 + st * 16 + quad * 4] = ov;
        uint2 ow;
        ow.x = pk2bf(oB[st][0] * invB, oB[st][1] * invB);
        ow.y = pk2bf(oB[st][2] * invB, oB[st][3] * invB);
        *(uint2*)&O[((long)(b * 2048 + qrB)) * 1024 + h * 64 + st * 16 + quad * 4] = ow;
    }
}

// ---------------- launch ----------------
extern "C" void kernel_launch(void* const* d_in, const int* in_sizes, int n_in,
                              void* d_out, int out_size, void* d_ws, size_t ws_size,
                              hipStream_t stream) {
    const float* x  = (const float*)d_in[0];
    const float* wq = (const float*)d_in[1];
    const float* bq = (const float*)d_in[2];
    const float* wk = (const float*)d_in[3];
    const float* bk = (const float*)d_in[4];
    const float* wv = (const float*)d_in[5];
    const float* bv = (const float*)d_in[6];
    const float* wo = (const float*)d_in[7];
    const float* bo = (const float*)d_in[8];

    char* w = (char*)d_ws;
    unsigned short* xb  = (unsigned short*)w;                    // 16MB
    unsigned short* wtq = (unsigned short*)(w + (16u << 20));    // wtq|wtk contiguous
    unsigned short* wtk = wtq + (1u << 20);
    unsigned short* wtv = wtk + (1u << 20);
    unsigned short* wto = wtv + (1u << 20);
    unsigned short* qb  = wto + (1u << 20);
    unsigned short* kb  = qb + (8u << 20);
    unsigned short* vb  = kb + (8u << 20);                       // V^T [B,H,DK,S]
    unsigned short* ob  = vb + (8u << 20);

    cvtx_kernel<<<8192, 256, 0, stream>>>(x, xb);
    dim3 tg(32, 32);
    wtrans_kernel<<<tg, 256, 0, stream>>>(wq, wtq);
    wtrans_kernel<<<tg, 256, 0, stream>>>(wk, wtk);
    wtrans_kernel<<<tg, 256, 0, stream>>>(wv, wtv);
    wtrans_kernel<<<tg, 256, 0, stream>>>(wo, wto);
    gemm_qk_kernel<<<dim3(16, 64), 256, 0, stream>>>(xb, wtq, bq, bk, qb, kb);
    gemm_v_kernel<<<dim3(8, 64), 256, 0, stream>>>(xb, wtv, bv, vb);
    attn_kernel<<<1024, 256, 0, stream>>>(qb, kb, vb, ob);
    gemm_out_kernel<<<dim3(8, 64), 256, 0, stream>>>(ob, wto, bo, (float*)d_out);
}

// Round 6
// 280.098 us; speedup vs baseline: 1.2530x; 1.1271x over previous
//
#include <hip/hip_runtime.h>

// MultiHeadAttention: B=4, S=2048, D=1024, H=16, DK=64
// cvt x->bf16; transpose weights->bf16 [N][K]; QK GEMM (Q pre-scaled by
// 1/8*log2e), V GEMM (writes V^T); flash attention (no-max softmax, masked
// only on diagonal tiles); output GEMM. All GEMMs: BK=64, XOR-swizzled LDS,
// global_load_lds width-16, XCD-stripe block swizzle for L2 locality.

typedef __attribute__((ext_vector_type(8))) short short8;
typedef __attribute__((ext_vector_type(4))) float floatx4;
typedef __attribute__((ext_vector_type(4))) unsigned short ushort4v;

#define SCLF (0.125f * 1.44269504f)

__device__ __forceinline__ unsigned short f2bf(float f) {
    unsigned int u = __float_as_uint(f);
    unsigned int r = (u + 0x7fffu + ((u >> 16) & 1u)) >> 16;
    return (unsigned short)r;
}

__device__ __forceinline__ unsigned int pk2bf(float lo, float hi) {
    return __builtin_amdgcn_perm(__float_as_uint(hi), __float_as_uint(lo), 0x07060302u);
}

__device__ __forceinline__ void gll16(const unsigned short* g, unsigned short* l) {
    __builtin_amdgcn_global_load_lds(
        (const __attribute__((address_space(1))) unsigned int*)g,
        (__attribute__((address_space(3))) unsigned int*)l, 16, 0, 0);
}

// XCD-stripe swizzle: lid&7 (~XCD) picks an M-stripe so each XCD re-reads
// only its own A stripe through its private L2.
__device__ __forceinline__ void xcd_tile(int nx, int& m0, int& n0) {
    int lid = blockIdx.y * nx + blockIdx.x;
    int grp = lid & 7;
    int inner = lid >> 3;
    int m_per = (gridDim.y + 7) >> 3;
    int my = grp * m_per + inner / nx;
    int mx = inner % nx;
    m0 = my * 128; n0 = mx * 128;
}

// ---------------- convert x (fp32 -> bf16) ----------------
__global__ void cvtx_kernel(const float* __restrict__ x, unsigned short* __restrict__ xb) {
    int i = (blockIdx.x * 256 + threadIdx.x) * 4;
    float4 v = *(const float4*)&x[i];
    ushort4v o;
    o.x = f2bf(v.x); o.y = f2bf(v.y); o.z = f2bf(v.z); o.w = f2bf(v.w);
    *(ushort4v*)&xb[i] = o;
}

// ---------------- transpose + convert weight: w[K][N] fp32 -> wt[N][K] bf16 ----------------
__global__ void wtrans_kernel(const float* __restrict__ w, unsigned short* __restrict__ wt) {
    __shared__ float t[32][33];
    int kb = blockIdx.y * 32, nb = blockIdx.x * 32;
    int col = threadIdx.x & 31, rw = threadIdx.x >> 5;
#pragma unroll
    for (int i = 0; i < 4; i++) {
        int row = rw + i * 8;
        t[row][col] = w[(kb + row) * 1024 + nb + col];
    }
    __syncthreads();
#pragma unroll
    for (int i = 0; i < 4; i++) {
        int row = rw + i * 8;
        wt[(nb + row) * 1024 + kb + col] = f2bf(t[col][row]);
    }
}

// ---------------- GEMM core: BK=64, XOR-swizzled LDS ----------------
__device__ __forceinline__ short8 ldsr(const unsigned short* p) { return *(const short8*)p; }

template <bool SW>
__device__ __forceinline__ void gemm_core(const unsigned short* __restrict__ A,
                                          const unsigned short* __restrict__ Bt,
                                          unsigned short* As, unsigned short* Bs,
                                          int m0, int n0, int K, floatx4 (&acc)[4][4]) {
    int tid = threadIdx.x;
    int lane = tid & 63, wave = tid >> 6;
    int wr = wave >> 1, wc = wave & 1;
    int quad = lane >> 4, l15 = lane & 15, l7 = l15 & 7;
    int rsub = lane >> 3;
    int gl = (lane & 7) ^ rsub;
    floatx4 zero4 = {0.f, 0.f, 0.f, 0.f};
#pragma unroll
    for (int i = 0; i < 4; i++)
#pragma unroll
        for (int j = 0; j < 4; j++) acc[i][j] = zero4;

    for (int k0 = 0; k0 < K; k0 += 64) {
#pragma unroll
        for (int p = 0; p < 4; p++) {
            int idx = (wave * 4 + p) * 64 + lane;
            int row = (wave * 4 + p) * 8 + rsub;
            gll16(&A[(m0 + row) * K + k0 + gl * 8], &As[idx * 8]);
            gll16(&Bt[(n0 + row) * K + k0 + gl * 8], &Bs[idx * 8]);
        }
        __syncthreads();
#pragma unroll
        for (int kk = 0; kk < 2; kk++) {
            short8 af[4], bf[4];
#pragma unroll
            for (int mt = 0; mt < 4; mt++) {
                int r = wr * 64 + mt * 16 + l15;
                af[mt] = ldsr(&As[r * 64 + (((kk * 4 + quad) ^ l7) * 8)]);
            }
#pragma unroll
            for (int nt = 0; nt < 4; nt++) {
                int r = wc * 64 + nt * 16 + l15;
                bf[nt] = ldsr(&Bs[r * 64 + (((kk * 4 + quad) ^ l7) * 8)]);
            }
#pragma unroll
            for (int mt = 0; mt < 4; mt++)
#pragma unroll
                for (int nt = 0; nt < 4; nt++) {
                    if (SW)
                        acc[mt][nt] = __builtin_amdgcn_mfma_f32_16x16x32_bf16(bf[nt], af[mt], acc[mt][nt], 0, 0, 0);
                    else
                        acc[mt][nt] = __builtin_amdgcn_mfma_f32_16x16x32_bf16(af[mt], bf[nt], acc[mt][nt], 0, 0, 0);
                }
        }
        __syncthreads();
    }
}

// ---------------- Q/K GEMM (swapped): N spans wtq|wtk; Q pre-scaled ----------------
__global__ __launch_bounds__(256) void gemm_qk_kernel(
    const unsigned short* __restrict__ xb, const unsigned short* __restrict__ wt,
    const float* __restrict__ bq, const float* __restrict__ bk,
    unsigned short* __restrict__ qo, unsigned short* __restrict__ ko) {
    __shared__ __align__(16) unsigned short As[128 * 64];
    __shared__ __align__(16) unsigned short Bs[128 * 64];
    int m0, n0;
    xcd_tile(16, m0, n0);
    floatx4 acc[4][4];
    gemm_core<true>(xb, wt, As, Bs, m0, n0, 1024, acc);

    int which = n0 >> 10;
    const float* bias = which ? bk : bq;
    unsigned short* dst = which ? ko : qo;
    float sc = which ? 1.0f : SCLF;
    int tid = threadIdx.x, lane = tid & 63, wave = tid >> 6;
    int wr = wave >> 1, wc = wave & 1, quad = lane >> 4, l15 = lane & 15;
#pragma unroll
    for (int mt = 0; mt < 4; mt++)
#pragma unroll
        for (int nt = 0; nt < 4; nt++) {
            int tok = m0 + wr * 64 + mt * 16 + l15;
            int b = tok >> 11, s = tok & 2047;
            int colf = (n0 + wc * 64 + nt * 16 + quad * 4) & 1023;
            float4 bb = *(const float4*)&bias[colf];
            int h = colf >> 6, dk = colf & 63;
            ushort4v o;
            o.x = f2bf((acc[mt][nt][0] + bb.x) * sc);
            o.y = f2bf((acc[mt][nt][1] + bb.y) * sc);
            o.z = f2bf((acc[mt][nt][2] + bb.z) * sc);
            o.w = f2bf((acc[mt][nt][3] + bb.w) * sc);
            *(ushort4v*)&dst[((long)((b * 16 + h) * 2048 + s)) * 64 + dk] = o;
        }
}

// ---------------- V GEMM (normal): writes V^T [B,H,DK,S] ----------------
__global__ __launch_bounds__(256) void gemm_v_kernel(
    const unsigned short* __restrict__ xb, const unsigned short* __restrict__ wtv,
    const float* __restrict__ bv, unsigned short* __restrict__ vo) {
    __shared__ __align__(16) unsigned short As[128 * 64];
    __shared__ __align__(16) unsigned short Bs[128 * 64];
    int m0, n0;
    xcd_tile(8, m0, n0);
    floatx4 acc[4][4];
    gemm_core<false>(xb, wtv, As, Bs, m0, n0, 1024, acc);

    int tid = threadIdx.x, lane = tid & 63, wave = tid >> 6;
    int wr = wave >> 1, wc = wave & 1, quad = lane >> 4, l15 = lane & 15;
#pragma unroll
    for (int mt = 0; mt < 4; mt++)
#pragma unroll
        for (int nt = 0; nt < 4; nt++) {
            int tok0 = m0 + wr * 64 + mt * 16 + quad * 4;
            int b = tok0 >> 11, s = tok0 & 2047;
            int colf = n0 + wc * 64 + nt * 16 + l15;
            int h = colf >> 6, dk = colf & 63;
            float bb = bv[colf];
            ushort4v o;
            o.x = f2bf(acc[mt][nt][0] + bb);
            o.y = f2bf(acc[mt][nt][1] + bb);
            o.z = f2bf(acc[mt][nt][2] + bb);
            o.w = f2bf(acc[mt][nt][3] + bb);
            *(ushort4v*)&vo[((long)((b * 16 + h) * 64 + dk)) * 2048 + s] = o;
        }
}

// ---------------- output GEMM (swapped): fp32 out, float4 stores ----------------
__global__ __launch_bounds__(256) void gemm_out_kernel(
    const unsigned short* __restrict__ ob, const unsigned short* __restrict__ wto,
    const float* __restrict__ bo, float* __restrict__ out) {
    __shared__ __align__(16) unsigned short As[128 * 64];
    __shared__ __align__(16) unsigned short Bs[128 * 64];
    int m0, n0;
    xcd_tile(8, m0, n0);
    floatx4 acc[4][4];
    gemm_core<true>(ob, wto, As, Bs, m0, n0, 1024, acc);

    int tid = threadIdx.x, lane = tid & 63, wave = tid >> 6;
    int wr = wave >> 1, wc = wave & 1, quad = lane >> 4, l15 = lane & 15;
#pragma unroll
    for (int mt = 0; mt < 4; mt++)
#pragma unroll
        for (int nt = 0; nt < 4; nt++) {
            int tok = m0 + wr * 64 + mt * 16 + l15;
            int cg = n0 + wc * 64 + nt * 16 + quad * 4;
            float4 bb = *(const float4*)&bo[cg];
            float4 o;
            o.x = acc[mt][nt][0] + bb.x;
            o.y = acc[mt][nt][1] + bb.y;
            o.z = acc[mt][nt][2] + bb.z;
            o.w = acc[mt][nt][3] + bb.w;
            *(float4*)&out[(long)tok * 1024 + cg] = o;
        }
}

// ---------------- flash attention (causal), 128 q-rows/block ----------------
// Q pre-scaled by 1/8*log2e, so p = exp2(score) directly. Causal masking only
// on the two diagonal tiles (uniform scalar branches); off-diagonal body has
// zero mask VALU.
__device__ __forceinline__ void stage_kv(const unsigned short* __restrict__ Kg,
                                         const unsigned short* __restrict__ Vg,
                                         unsigned short* Ks, unsigned short* Vs,
                                         int lane, int wave) {
    int rsub = lane >> 3;
    int g = (lane & 7) ^ rsub;
#pragma unroll
    for (int p = 0; p < 2; p++) {
        int chunk = wave * 2 + p;
        int r = chunk * 8 + rsub;
        gll16(&Kg[r * 64 + g * 8], &Ks[chunk * 512]);
        gll16(&Vg[r * 2048 + g * 8], &Vs[chunk * 512]);
    }
}

__global__ __launch_bounds__(256, 4) void attn_kernel(
    const unsigned short* __restrict__ Q, const unsigned short* __restrict__ Kk,
    const unsigned short* __restrict__ Vt, unsigned short* __restrict__ O) {
    __shared__ __align__(16) unsigned short Ks[2][8 * 512];
    __shared__ __align__(16) unsigned short Vs[2][8 * 512];
    __shared__ __align__(16) unsigned short Ps[4 * 16 * 64];

    int bid = blockIdx.x;
    int qt = 15 - (bid >> 6);
    int bh = bid & 63;
    int q0 = qt * 128;
    long base = (long)bh * 2048 * 64;
    long vbase = (long)bh * 64 * 2048;
    int tid = threadIdx.x, lane = tid & 63, wave = tid >> 6;
    int quad = lane >> 4, l15 = lane & 15, l7 = l15 & 7;

    short8 qfA[2], qfB[2];
    int qrA = q0 + wave * 16 + l15;
    int qrB = qrA + 64;
    qfA[0] = *(const short8*)&Q[base + qrA * 64 + quad * 8];
    qfA[1] = *(const short8*)&Q[base + qrA * 64 + 32 + quad * 8];
    qfB[0] = *(const short8*)&Q[base + qrB * 64 + quad * 8];
    qfB[1] = *(const short8*)&Q[base + qrB * 64 + 32 + quad * 8];

    float lA = 0.f, lB = 0.f;
    floatx4 oA[4], oB[4];
    floatx4 zero4 = {0.f, 0.f, 0.f, 0.f};
#pragma unroll
    for (int st = 0; st < 4; st++) { oA[st] = zero4; oB[st] = zero4; }

    unsigned short* myP = &Ps[(wave * 16) * 64];
    int pw_off = l15 * 64 + (quad & 1) * 4;
    int pr0 = l15 * 64 + ((quad ^ l7) * 8);
    int pr1 = l15 * 64 + (((4 + quad) ^ l7) * 8);

    int ktmax = 2 * qt + 1;
    stage_kv(&Kk[base], &Vt[vbase], Ks[0], Vs[0], lane, wave);
    __syncthreads();

    for (int kt = 0; kt <= ktmax; kt++) {
        int cur = kt & 1;
        if (kt < ktmax)
            stage_kv(&Kk[base + (long)(kt + 1) * 64 * 64], &Vt[vbase + (kt + 1) * 64],
                     Ks[cur ^ 1], Vs[cur ^ 1], lane, wave);
        bool doA = (kt < ktmax);          // uniform
        bool maskA = (kt == ktmax - 1);   // uniform: A diagonal tile
        bool maskB = (kt == ktmax);       // uniform: B diagonal tile

        floatx4 saA[4], saB[4];
#pragma unroll
        for (int st = 0; st < 4; st++) {
            int row = st * 16 + l15;
            short8 kf0 = ldsr(&Ks[cur][row * 64 + ((quad ^ l7) * 8)]);
            short8 kf1 = ldsr(&Ks[cur][row * 64 + (((4 + quad) ^ l7) * 8)]);
            saB[st] = __builtin_amdgcn_mfma_f32_16x16x32_bf16(kf0, qfB[0], zero4, 0, 0, 0);
            saB[st] = __builtin_amdgcn_mfma_f32_16x16x32_bf16(kf1, qfB[1], saB[st], 0, 0, 0);
            if (doA) {
                saA[st] = __builtin_amdgcn_mfma_f32_16x16x32_bf16(kf0, qfA[0], zero4, 0, 0, 0);
                saA[st] = __builtin_amdgcn_mfma_f32_16x16x32_bf16(kf1, qfA[1], saA[st], 0, 0, 0);
            }
        }

        int kg0 = kt * 64 + quad * 4;
        short8 pfB0, pfB1, pfA0, pfA1;
        {
            float p[4][4];
#pragma unroll
            for (int st = 0; st < 4; st++)
#pragma unroll
                for (int r = 0; r < 4; r++)
                    p[st][r] = __builtin_amdgcn_exp2f(saB[st][r]);
            if (maskB) {
#pragma unroll
                for (int st = 0; st < 4; st++)
#pragma unroll
                    for (int r = 0; r < 4; r++)
                        if (kg0 + st * 16 + r > qrB) p[st][r] = 0.f;
            }
            float rs = 0.f;
#pragma unroll
            for (int st = 0; st < 4; st++) {
                rs += p[st][0] + p[st][1] + p[st][2] + p[st][3];
                uint2 pw;
                pw.x = pk2bf(p[st][0], p[st][1]);
                pw.y = pk2bf(p[st][2], p[st][3]);
                *(uint2*)&myP[pw_off + (((st * 2 + (quad >> 1)) ^ l7) * 8)] = pw;
            }
            rs += __shfl_xor(rs, 16, 64);
            rs += __shfl_xor(rs, 32, 64);
            lB += rs;
            pfB0 = ldsr(&myP[pr0]);
            pfB1 = ldsr(&myP[pr1]);
        }
        if (doA) {
            float p[4][4];
#pragma unroll
            for (int st = 0; st < 4; st++)
#pragma unroll
                for (int r = 0; r < 4; r++)
                    p[st][r] = __builtin_amdgcn_exp2f(saA[st][r]);
            if (maskA) {
#pragma unroll
                for (int st = 0; st < 4; st++)
#pragma unroll
                    for (int r = 0; r < 4; r++)
                        if (kg0 + st * 16 + r > qrA) p[st][r] = 0.f;
            }
            float rs = 0.f;
#pragma unroll
            for (int st = 0; st < 4; st++) {
                rs += p[st][0] + p[st][1] + p[st][2] + p[st][3];
                uint2 pw;
                pw.x = pk2bf(p[st][0], p[st][1]);
                pw.y = pk2bf(p[st][2], p[st][3]);
                *(uint2*)&myP[pw_off + (((st * 2 + (quad >> 1)) ^ l7) * 8)] = pw;
            }
            rs += __shfl_xor(rs, 16, 64);
            rs += __shfl_xor(rs, 32, 64);
            lA += rs;
            pfA0 = ldsr(&myP[pr0]);
            pfA1 = ldsr(&myP[pr1]);
        }

#pragma unroll
        for (int st = 0; st < 4; st++) {
            int row = st * 16 + l15;
            short8 vf0 = ldsr(&Vs[cur][row * 64 + ((quad ^ l7) * 8)]);
            short8 vf1 = ldsr(&Vs[cur][row * 64 + (((4 + quad) ^ l7) * 8)]);
            oB[st] = __builtin_amdgcn_mfma_f32_16x16x32_bf16(vf0, pfB0, oB[st], 0, 0, 0);
            oB[st] = __builtin_amdgcn_mfma_f32_16x16x32_bf16(vf1, pfB1, oB[st], 0, 0, 0);
            if (doA) {
                oA[st] = __builtin_amdgcn_mfma_f32_16x16x32_bf16(vf0, pfA0, oA[st], 0, 0, 0);
                oA[st] = __builtin_amdgcn_mfma_f32_16x16x32_bf16(vf1, pfA1, oA[st], 0, 0, 0);
            }
        }
        __syncthreads();
    }

    int b = bh >> 4, h = bh & 15;
    float invA = 1.f / lA, invB = 1.f / lB;
#pragma unroll
    for (int st = 0; st < 4; st++) {
        uint2 ov;
        ov.x = pk2bf(oA[st][0] * invA, oA[st][1] * invA);
        ov.y = pk2bf(oA[st][2] * invA, oA[st][3] * invA);
        *(uint2*)&O[((long)(b * 2048 + qrA)) * 1024 + h * 64 + st * 16 + quad * 4] = ov;
        uint2 ow;
        ow.x = pk2bf(oB[st][0] * invB, oB[st][1] * invB);
        ow.y = pk2bf(oB[st][2] * invB, oB[st][3] * invB);
        *(uint2*)&O[((long)(b * 2048 + qrB)) * 1024 + h * 64 + st * 16 + quad * 4] = ow;
    }
}

// ---------------- launch ----------------
extern "C" void kernel_launch(void* const* d_in, const int* in_sizes, int n_in,
                              void* d_out, int out_size, void* d_ws, size_t ws_size,
                              hipStream_t stream) {
    const float* x  = (const float*)d_in[0];
    const float* wq = (const float*)d_in[1];
    const float* bq = (const float*)d_in[2];
    const float* wk = (const float*)d_in[3];
    const float* bk = (const float*)d_in[4];
    const float* wv = (const float*)d_in[5];
    const float* bv = (const float*)d_in[6];
    const float* wo = (const float*)d_in[7];
    const float* bo = (const float*)d_in[8];

    char* w = (char*)d_ws;
    unsigned short* xb  = (unsigned short*)w;
    unsigned short* wtq = (unsigned short*)(w + (16u << 20));
    unsigned short* wtk = wtq + (1u << 20);
    unsigned short* wtv = wtk + (1u << 20);
    unsigned short* wto = wtv + (1u << 20);
    unsigned short* qb  = wto + (1u << 20);
    unsigned short* kb  = qb + (8u << 20);
    unsigned short* vb  = kb + (8u << 20);
    unsigned short* ob  = vb + (8u << 20);

    cvtx_kernel<<<8192, 256, 0, stream>>>(x, xb);
    dim3 tg(32, 32);
    wtrans_kernel<<<tg, 256, 0, stream>>>(wq, wtq);
    wtrans_kernel<<<tg, 256, 0, stream>>>(wk, wtk);
    wtrans_kernel<<<tg, 256, 0, stream>>>(wv, wtv);
    wtrans_kernel<<<tg, 256, 0, stream>>>(wo, wto);
    gemm_qk_kernel<<<dim3(16, 64), 256, 0, stream>>>(xb, wtq, bq, bk, qb, kb);
    gemm_v_kernel<<<dim3(8, 64), 256, 0, stream>>>(xb, wtv, bv, vb);
    attn_kernel<<<1024, 256, 0, stream>>>(qb, kb, vb, ob);
    gemm_out_kernel<<<dim3(8, 64), 256, 0, stream>>>(ob, wto, bo, (float*)d_out);
}

// Round 7
// 271.756 us; speedup vs baseline: 1.2914x; 1.0307x over previous
//
#include <hip/hip_runtime.h>

// MultiHeadAttention: B=4, S=2048, D=1024, H=16, DK=64
// 5 dispatches: cvt x->bf16; fused weight transpose (z=4); fused projection
// GEMM N=3072 (Q pre-scaled 1/8*log2e, K, V^T epilogues); flash attention
// (no-max softmax, diagonal-only masking); output GEMM -> fp32.
// GEMMs: BK=64, XOR-swizzled LDS, global_load_lds width-16, XCD-stripe swizzle.

typedef __attribute__((ext_vector_type(8))) short short8;
typedef __attribute__((ext_vector_type(4))) float floatx4;
typedef __attribute__((ext_vector_type(4))) unsigned short ushort4v;

#define SCLF (0.125f * 1.44269504f)

__device__ __forceinline__ unsigned short f2bf(float f) {
    unsigned int u = __float_as_uint(f);
    unsigned int r = (u + 0x7fffu + ((u >> 16) & 1u)) >> 16;
    return (unsigned short)r;
}

__device__ __forceinline__ unsigned int pk2bf(float lo, float hi) {
    return __builtin_amdgcn_perm(__float_as_uint(hi), __float_as_uint(lo), 0x07060302u);
}

__device__ __forceinline__ void gll16(const unsigned short* g, unsigned short* l) {
    __builtin_amdgcn_global_load_lds(
        (const __attribute__((address_space(1))) unsigned int*)g,
        (__attribute__((address_space(3))) unsigned int*)l, 16, 0, 0);
}

// XCD-stripe swizzle: lid&7 (~XCD) picks an M-stripe so each XCD re-reads
// only its own A stripe through its private L2.
__device__ __forceinline__ void xcd_tile(int nx, int& m0, int& n0) {
    int lid = blockIdx.y * nx + blockIdx.x;
    int grp = lid & 7;
    int inner = lid >> 3;
    int m_per = (gridDim.y + 7) >> 3;
    int my = grp * m_per + inner / nx;
    int mx = inner % nx;
    m0 = my * 128; n0 = mx * 128;
}

// ---------------- convert x (fp32 -> bf16) ----------------
__global__ void cvtx_kernel(const float* __restrict__ x, unsigned short* __restrict__ xb) {
    int i = (blockIdx.x * 256 + threadIdx.x) * 4;
    float4 v = *(const float4*)&x[i];
    ushort4v o;
    o.x = f2bf(v.x); o.y = f2bf(v.y); o.z = f2bf(v.z); o.w = f2bf(v.w);
    *(ushort4v*)&xb[i] = o;
}

// ---------------- fused transpose+convert: 4 weights, z picks which ----------------
__global__ void wtrans_kernel(const float* __restrict__ wq, const float* __restrict__ wk,
                              const float* __restrict__ wv, const float* __restrict__ wo,
                              unsigned short* __restrict__ wtbase) {
    __shared__ float t[32][33];
    int z = blockIdx.z;
    const float* w = (z == 0) ? wq : (z == 1) ? wk : (z == 2) ? wv : wo;
    unsigned short* wt = wtbase + ((long)z << 20);
    int kb = blockIdx.y * 32, nb = blockIdx.x * 32;
    int col = threadIdx.x & 31, rw = threadIdx.x >> 5;
#pragma unroll
    for (int i = 0; i < 4; i++) {
        int row = rw + i * 8;
        t[row][col] = w[(kb + row) * 1024 + nb + col];
    }
    __syncthreads();
#pragma unroll
    for (int i = 0; i < 4; i++) {
        int row = rw + i * 8;
        wt[(nb + row) * 1024 + kb + col] = f2bf(t[col][row]);
    }
}

// ---------------- GEMM core: BK=64, XOR-swizzled LDS ----------------
__device__ __forceinline__ short8 ldsr(const unsigned short* p) { return *(const short8*)p; }

template <bool SW>
__device__ __forceinline__ void gemm_core(const unsigned short* __restrict__ A,
                                          const unsigned short* __restrict__ Bt,
                                          unsigned short* As, unsigned short* Bs,
                                          int m0, int n0, int K, floatx4 (&acc)[4][4]) {
    int tid = threadIdx.x;
    int lane = tid & 63, wave = tid >> 6;
    int wr = wave >> 1, wc = wave & 1;
    int quad = lane >> 4, l15 = lane & 15, l7 = l15 & 7;
    int rsub = lane >> 3;
    int gl = (lane & 7) ^ rsub;
    floatx4 zero4 = {0.f, 0.f, 0.f, 0.f};
#pragma unroll
    for (int i = 0; i < 4; i++)
#pragma unroll
        for (int j = 0; j < 4; j++) acc[i][j] = zero4;

    for (int k0 = 0; k0 < K; k0 += 64) {
#pragma unroll
        for (int p = 0; p < 4; p++) {
            int idx = (wave * 4 + p) * 64 + lane;
            int row = (wave * 4 + p) * 8 + rsub;
            gll16(&A[(m0 + row) * K + k0 + gl * 8], &As[idx * 8]);
            gll16(&Bt[(n0 + row) * K + k0 + gl * 8], &Bs[idx * 8]);
        }
        __syncthreads();
#pragma unroll
        for (int kk = 0; kk < 2; kk++) {
            short8 af[4], bf[4];
#pragma unroll
            for (int mt = 0; mt < 4; mt++) {
                int r = wr * 64 + mt * 16 + l15;
                af[mt] = ldsr(&As[r * 64 + (((kk * 4 + quad) ^ l7) * 8)]);
            }
#pragma unroll
            for (int nt = 0; nt < 4; nt++) {
                int r = wc * 64 + nt * 16 + l15;
                bf[nt] = ldsr(&Bs[r * 64 + (((kk * 4 + quad) ^ l7) * 8)]);
            }
#pragma unroll
            for (int mt = 0; mt < 4; mt++)
#pragma unroll
                for (int nt = 0; nt < 4; nt++) {
                    if (SW)
                        acc[mt][nt] = __builtin_amdgcn_mfma_f32_16x16x32_bf16(bf[nt], af[mt], acc[mt][nt], 0, 0, 0);
                    else
                        acc[mt][nt] = __builtin_amdgcn_mfma_f32_16x16x32_bf16(af[mt], bf[nt], acc[mt][nt], 0, 0, 0);
                }
        }
        __syncthreads();
    }
}

// ---------------- fused projection GEMM: N=3072 over wtq|wtk|wtv ----------------
// n0 in [0,1024): Q (swapped, pre-scaled); [1024,2048): K (swapped);
// [2048,3072): V (normal, writes V^T [B,H,DK,S]).
__global__ __launch_bounds__(256) void proj_kernel(
    const unsigned short* __restrict__ xb, const unsigned short* __restrict__ wt,
    const float* __restrict__ bq, const float* __restrict__ bk, const float* __restrict__ bv,
    unsigned short* __restrict__ qo, unsigned short* __restrict__ ko,
    unsigned short* __restrict__ vo) {
    __shared__ __align__(16) unsigned short As[128 * 64];
    __shared__ __align__(16) unsigned short Bs[128 * 64];
    int m0, n0;
    xcd_tile(24, m0, n0);
    floatx4 acc[4][4];
    int tid = threadIdx.x, lane = tid & 63, wave = tid >> 6;
    int wr = wave >> 1, wc = wave & 1, quad = lane >> 4, l15 = lane & 15;

    if (n0 < 2048) {
        gemm_core<true>(xb, wt, As, Bs, m0, n0, 1024, acc);
        int which = n0 >> 10;
        const float* bias = which ? bk : bq;
        unsigned short* dst = which ? ko : qo;
        float sc = which ? 1.0f : SCLF;
#pragma unroll
        for (int mt = 0; mt < 4; mt++)
#pragma unroll
            for (int nt = 0; nt < 4; nt++) {
                int tok = m0 + wr * 64 + mt * 16 + l15;
                int b = tok >> 11, s = tok & 2047;
                int colf = (n0 + wc * 64 + nt * 16 + quad * 4) & 1023;
                float4 bb = *(const float4*)&bias[colf];
                int h = colf >> 6, dk = colf & 63;
                ushort4v o;
                o.x = f2bf((acc[mt][nt][0] + bb.x) * sc);
                o.y = f2bf((acc[mt][nt][1] + bb.y) * sc);
                o.z = f2bf((acc[mt][nt][2] + bb.z) * sc);
                o.w = f2bf((acc[mt][nt][3] + bb.w) * sc);
                *(ushort4v*)&dst[((long)((b * 16 + h) * 2048 + s)) * 64 + dk] = o;
            }
    } else {
        gemm_core<false>(xb, wt, As, Bs, m0, n0, 1024, acc);
#pragma unroll
        for (int mt = 0; mt < 4; mt++)
#pragma unroll
            for (int nt = 0; nt < 4; nt++) {
                int tok0 = m0 + wr * 64 + mt * 16 + quad * 4;
                int b = tok0 >> 11, s = tok0 & 2047;
                int colf = (n0 & 1023) + wc * 64 + nt * 16 + l15;
                int h = colf >> 6, dk = colf & 63;
                float bb = bv[colf];
                ushort4v o;
                o.x = f2bf(acc[mt][nt][0] + bb);
                o.y = f2bf(acc[mt][nt][1] + bb);
                o.z = f2bf(acc[mt][nt][2] + bb);
                o.w = f2bf(acc[mt][nt][3] + bb);
                *(ushort4v*)&vo[((long)((b * 16 + h) * 64 + dk)) * 2048 + s] = o;
            }
    }
}

// ---------------- output GEMM (swapped): fp32 out, float4 stores ----------------
__global__ __launch_bounds__(256) void gemm_out_kernel(
    const unsigned short* __restrict__ ob, const unsigned short* __restrict__ wto,
    const float* __restrict__ bo, float* __restrict__ out) {
    __shared__ __align__(16) unsigned short As[128 * 64];
    __shared__ __align__(16) unsigned short Bs[128 * 64];
    int m0, n0;
    xcd_tile(8, m0, n0);
    floatx4 acc[4][4];
    gemm_core<true>(ob, wto, As, Bs, m0, n0, 1024, acc);

    int tid = threadIdx.x, lane = tid & 63, wave = tid >> 6;
    int wr = wave >> 1, wc = wave & 1, quad = lane >> 4, l15 = lane & 15;
#pragma unroll
    for (int mt = 0; mt < 4; mt++)
#pragma unroll
        for (int nt = 0; nt < 4; nt++) {
            int tok = m0 + wr * 64 + mt * 16 + l15;
            int cg = n0 + wc * 64 + nt * 16 + quad * 4;
            float4 bb = *(const float4*)&bo[cg];
            float4 o;
            o.x = acc[mt][nt][0] + bb.x;
            o.y = acc[mt][nt][1] + bb.y;
            o.z = acc[mt][nt][2] + bb.z;
            o.w = acc[mt][nt][3] + bb.w;
            *(float4*)&out[(long)tok * 1024 + cg] = o;
        }
}

// ---------------- flash attention (causal), 128 q-rows/block ----------------
__device__ __forceinline__ void stage_kv(const unsigned short* __restrict__ Kg,
                                         const unsigned short* __restrict__ Vg,
                                         unsigned short* Ks, unsigned short* Vs,
                                         int lane, int wave) {
    int rsub = lane >> 3;
    int g = (lane & 7) ^ rsub;
#pragma unroll
    for (int p = 0; p < 2; p++) {
        int chunk = wave * 2 + p;
        int r = chunk * 8 + rsub;
        gll16(&Kg[r * 64 + g * 8], &Ks[chunk * 512]);
        gll16(&Vg[r * 2048 + g * 8], &Vs[chunk * 512]);
    }
}

__global__ __launch_bounds__(256, 4) void attn_kernel(
    const unsigned short* __restrict__ Q, const unsigned short* __restrict__ Kk,
    const unsigned short* __restrict__ Vt, unsigned short* __restrict__ O) {
    __shared__ __align__(16) unsigned short Ks[2][8 * 512];
    __shared__ __align__(16) unsigned short Vs[2][8 * 512];
    __shared__ __align__(16) unsigned short Ps[4 * 16 * 64];

    int bid = blockIdx.x;
    int qt = 15 - (bid >> 6);
    int bh = bid & 63;
    int q0 = qt * 128;
    long base = (long)bh * 2048 * 64;
    long vbase = (long)bh * 64 * 2048;
    int tid = threadIdx.x, lane = tid & 63, wave = tid >> 6;
    int quad = lane >> 4, l15 = lane & 15, l7 = l15 & 7;

    short8 qfA[2], qfB[2];
    int qrA = q0 + wave * 16 + l15;
    int qrB = qrA + 64;
    qfA[0] = *(const short8*)&Q[base + qrA * 64 + quad * 8];
    qfA[1] = *(const short8*)&Q[base + qrA * 64 + 32 + quad * 8];
    qfB[0] = *(const short8*)&Q[base + qrB * 64 + quad * 8];
    qfB[1] = *(const short8*)&Q[base + qrB * 64 + 32 + quad * 8];

    float lA = 0.f, lB = 0.f;
    floatx4 oA[4], oB[4];
    floatx4 zero4 = {0.f, 0.f, 0.f, 0.f};
#pragma unroll
    for (int st = 0; st < 4; st++) { oA[st] = zero4; oB[st] = zero4; }

    unsigned short* myP = &Ps[(wave * 16) * 64];
    int pw_off = l15 * 64 + (quad & 1) * 4;
    int pr0 = l15 * 64 + ((quad ^ l7) * 8);
    int pr1 = l15 * 64 + (((4 + quad) ^ l7) * 8);

    int ktmax = 2 * qt + 1;
    stage_kv(&Kk[base], &Vt[vbase], Ks[0], Vs[0], lane, wave);
    __syncthreads();

    for (int kt = 0; kt <= ktmax; kt++) {
        int cur = kt & 1;
        if (kt < ktmax)
            stage_kv(&Kk[base + (long)(kt + 1) * 64 * 64], &Vt[vbase + (kt + 1) * 64],
                     Ks[cur ^ 1], Vs[cur ^ 1], lane, wave);
        bool doA = (kt < ktmax);
        bool maskA = (kt == ktmax - 1);
        bool maskB = (kt == ktmax);

        floatx4 saA[4], saB[4];
#pragma unroll
        for (int st = 0; st < 4; st++) {
            int row = st * 16 + l15;
            short8 kf0 = ldsr(&Ks[cur][row * 64 + ((quad ^ l7) * 8)]);
            short8 kf1 = ldsr(&Ks[cur][row * 64 + (((4 + quad) ^ l7) * 8)]);
            saB[st] = __builtin_amdgcn_mfma_f32_16x16x32_bf16(kf0, qfB[0], zero4, 0, 0, 0);
            saB[st] = __builtin_amdgcn_mfma_f32_16x16x32_bf16(kf1, qfB[1], saB[st], 0, 0, 0);
            if (doA) {
                saA[st] = __builtin_amdgcn_mfma_f32_16x16x32_bf16(kf0, qfA[0], zero4, 0, 0, 0);
                saA[st] = __builtin_amdgcn_mfma_f32_16x16x32_bf16(kf1, qfA[1], saA[st], 0, 0, 0);
            }
        }

        int kg0 = kt * 64 + quad * 4;
        short8 pfB0, pfB1, pfA0, pfA1;
        {
            float p[4][4];
#pragma unroll
            for (int st = 0; st < 4; st++)
#pragma unroll
                for (int r = 0; r < 4; r++)
                    p[st][r] = __builtin_amdgcn_exp2f(saB[st][r]);
            if (maskB) {
#pragma unroll
                for (int st = 0; st < 4; st++)
#pragma unroll
                    for (int r = 0; r < 4; r++)
                        if (kg0 + st * 16 + r > qrB) p[st][r] = 0.f;
            }
            float rs = 0.f;
#pragma unroll
            for (int st = 0; st < 4; st++) {
                rs += p[st][0] + p[st][1] + p[st][2] + p[st][3];
                uint2 pw;
                pw.x = pk2bf(p[st][0], p[st][1]);
                pw.y = pk2bf(p[st][2], p[st][3]);
                *(uint2*)&myP[pw_off + (((st * 2 + (quad >> 1)) ^ l7) * 8)] = pw;
            }
            rs += __shfl_xor(rs, 16, 64);
            rs += __shfl_xor(rs, 32, 64);
            lB += rs;
            pfB0 = ldsr(&myP[pr0]);
            pfB1 = ldsr(&myP[pr1]);
        }
        if (doA) {
            float p[4][4];
#pragma unroll
            for (int st = 0; st < 4; st++)
#pragma unroll
                for (int r = 0; r < 4; r++)
                    p[st][r] = __builtin_amdgcn_exp2f(saA[st][r]);
            if (maskA) {
#pragma unroll
                for (int st = 0; st < 4; st++)
#pragma unroll
                    for (int r = 0; r < 4; r++)
                        if (kg0 + st * 16 + r > qrA) p[st][r] = 0.f;
            }
            float rs = 0.f;
#pragma unroll
            for (int st = 0; st < 4; st++) {
                rs += p[st][0] + p[st][1] + p[st][2] + p[st][3];
                uint2 pw;
                pw.x = pk2bf(p[st][0], p[st][1]);
                pw.y = pk2bf(p[st][2], p[st][3]);
                *(uint2*)&myP[pw_off + (((st * 2 + (quad >> 1)) ^ l7) * 8)] = pw;
            }
            rs += __shfl_xor(rs, 16, 64);
            rs += __shfl_xor(rs, 32, 64);
            lA += rs;
            pfA0 = ldsr(&myP[pr0]);
            pfA1 = ldsr(&myP[pr1]);
        }

#pragma unroll
        for (int st = 0; st < 4; st++) {
            int row = st * 16 + l15;
            short8 vf0 = ldsr(&Vs[cur][row * 64 + ((quad ^ l7) * 8)]);
            short8 vf1 = ldsr(&Vs[cur][row * 64 + (((4 + quad) ^ l7) * 8)]);
            oB[st] = __builtin_amdgcn_mfma_f32_16x16x32_bf16(vf0, pfB0, oB[st], 0, 0, 0);
            oB[st] = __builtin_amdgcn_mfma_f32_16x16x32_bf16(vf1, pfB1, oB[st], 0, 0, 0);
            if (doA) {
                oA[st] = __builtin_amdgcn_mfma_f32_16x16x32_bf16(vf0, pfA0, oA[st], 0, 0, 0);
                oA[st] = __builtin_amdgcn_mfma_f32_16x16x32_bf16(vf1, pfA1, oA[st], 0, 0, 0);
            }
        }
        __syncthreads();
    }

    int b = bh >> 4, h = bh & 15;
    float invA = 1.f / lA, invB = 1.f / lB;
#pragma unroll
    for (int st = 0; st < 4; st++) {
        uint2 ov;
        ov.x = pk2bf(oA[st][0] * invA, oA[st][1] * invA);
        ov.y = pk2bf(oA[st][2] * invA, oA[st][3] * invA);
        *(uint2*)&O[((long)(b * 2048 + qrA)) * 1024 + h * 64 + st * 16 + quad * 4] = ov;
        uint2 ow;
        ow.x = pk2bf(oB[st][0] * invB, oB[st][1] * invB);
        ow.y = pk2bf(oB[st][2] * invB, oB[st][3] * invB);
        *(uint2*)&O[((long)(b * 2048 + qrB)) * 1024 + h * 64 + st * 16 + quad * 4] = ow;
    }
}

// ---------------- launch ----------------
extern "C" void kernel_launch(void* const* d_in, const int* in_sizes, int n_in,
                              void* d_out, int out_size, void* d_ws, size_t ws_size,
                              hipStream_t stream) {
    const float* x  = (const float*)d_in[0];
    const float* wq = (const float*)d_in[1];
    const float* bq = (const float*)d_in[2];
    const float* wk = (const float*)d_in[3];
    const float* bk = (const float*)d_in[4];
    const float* wv = (const float*)d_in[5];
    const float* bv = (const float*)d_in[6];
    const float* wo = (const float*)d_in[7];
    const float* bo = (const float*)d_in[8];

    char* w = (char*)d_ws;
    unsigned short* xb  = (unsigned short*)w;                    // 16MB
    unsigned short* wtq = (unsigned short*)(w + (16u << 20));    // wtq|wtk|wtv|wto contiguous
    unsigned short* wto = wtq + (3u << 20);
    unsigned short* qb  = wto + (1u << 20);
    unsigned short* kb  = qb + (8u << 20);
    unsigned short* vb  = kb + (8u << 20);                       // V^T [B,H,DK,S]
    unsigned short* ob  = vb + (8u << 20);

    cvtx_kernel<<<8192, 256, 0, stream>>>(x, xb);
    wtrans_kernel<<<dim3(32, 32, 4), 256, 0, stream>>>(wq, wk, wv, wo, wtq);
    proj_kernel<<<dim3(24, 64), 256, 0, stream>>>(xb, wtq, bq, bk, bv, qb, kb, vb);
    attn_kernel<<<1024, 256, 0, stream>>>(qb, kb, vb, ob);
    gemm_out_kernel<<<dim3(8, 64), 256, 0, stream>>>(ob, wto, bo, (float*)d_out);
}